// Round 7
// baseline (921.032 us; speedup 1.0000x reference)
//
#include <hip/hip_runtime.h>
#include <cstdint>
#include <cstddef>

#define TT 1000
#define NB 64000  // B*T

// ---------------------------------------------------------------------------
// NUMERICS CONTRACT: each z[n,o] is ONE ascending-k fp32 chain matching
// fmaf(s_k, W[k,o], acc), s_k in {0,1}. Exact identities used:
//   fmaf(1,W,acc) == W + acc      (single rounding, identical)
//   fmaf(0,W,acc) == acc          (skip)
//   acc += 0.0f   == acc bitwise  (acc never -0: chain starts +0, RN
//                                  exact-cancel gives +0, +0+(-0)=+0)
// => per-row ascending-k adds, with exhausted-chain steps adding 0.0f,
// is bit-identical. Do not reorder k within a row, do not tree-reduce.
//
// LEDGER: dense r0-r4 ~106us/gemm floor (busy 72us + immovable idle).
// r5 sparse serial: 127-145 cyc/k, latency-bound, VALUBusy 25%.
// r6 batch-4 within-row: 148us — adds chain into one acc, no real overlap.
// r7: 4 INDEPENDENT ROWS per wave in lockstep (independent loads AND adds,
// 4-deep by construction). Scalar pipe drives extraction; VALU does
// 4x(addr, cndmask-add x PO); exhausted chains add 0.0f (exact).
// ---------------------------------------------------------------------------

// ---------------------------------------------------------------------------
// Sparse GEMM: Z[r, bo:bo+OH] = sum_{k in mask(r)} Wlds[k, :] (ascending k)
// 1024 thr = 16 waves; each wave processes 4 rows (r, r+16, r+32, r+48)
// concurrently per 64-row group. W tile K x OH f32 in LDS, loaded once.
// Masks: KC u64 words per row (bit i of word c = k (c*64+i)), SGPR-hoisted.
// ---------------------------------------------------------------------------
template <int K, int KC, int OH, int PO>
__global__ __launch_bounds__(1024) void spmm(
    const unsigned long long* __restrict__ M, const float* __restrict__ Wt,
    float* __restrict__ Z, int Wld, int Zld, int Ostore, int rowsPerBlock) {
  __shared__ float Wl[K * OH];
  const int tid = threadIdx.x;
  const int lane = tid & 63;
  const int bo = blockIdx.y * OH;
  const int lo2 = lane * PO;

  // one-time W tile load (L2-resident source; grid reuses it)
  for (int i = tid; i < K * OH / 4; i += 1024) {
    int k = i / (OH / 4);
    int off = i - k * (OH / 4);
    *(float4*)&Wl[i * 4] = *(const float4*)&Wt[(size_t)k * Wld + bo + off * 4];
  }
  __syncthreads();

  const int wv = __builtin_amdgcn_readfirstlane(tid >> 6);
  const int r0 = blockIdx.x * rowsPerBlock;
  const int ngroups = rowsPerBlock >> 6;
  for (int g = 0; g < ngroups; g++) {
    const int rbase = r0 + g * 64 + wv;  // rows rbase + {0,16,32,48}
    // hoist 4 rows' mask words to SGPRs (wave-uniform)
    unsigned long long ms[4][KC];
#pragma unroll
    for (int q = 0; q < 4; q++) {
      const unsigned long long* mrow = M + (size_t)(rbase + q * 16) * KC;
#pragma unroll
      for (int c = 0; c < KC; c++) {
        unsigned long long mv = mrow[c];
        unsigned mlo = __builtin_amdgcn_readfirstlane((unsigned)mv);
        unsigned mhi = __builtin_amdgcn_readfirstlane((unsigned)(mv >> 32));
        ms[q][c] = ((unsigned long long)mhi << 32) | mlo;
      }
    }
    float ax[4] = {0.f, 0.f, 0.f, 0.f};
    float ay[4] = {0.f, 0.f, 0.f, 0.f};
#pragma unroll
    for (int c = 0; c < KC; c++) {
      unsigned long long m0 = ms[0][c], m1 = ms[1][c];
      unsigned long long m2 = ms[2][c], m3 = ms[3][c];
      const float* Wb = &Wl[c * 64 * OH];
      int n0 = __builtin_popcountll(m0), n1 = __builtin_popcountll(m1);
      int n2 = __builtin_popcountll(m2), n3 = __builtin_popcountll(m3);
      int it = n0 > n1 ? n0 : n1;
      int it2 = n2 > n3 ? n2 : n3;
      if (it2 > it) it = it2;
      for (int s = 0; s < it; s++) {
        // extract next bit of each chain (scalar pipe); exhausted -> k=0
        bool v0 = m0 != 0, v1 = m1 != 0, v2 = m2 != 0, v3 = m3 != 0;
        int k0 = v0 ? __builtin_ctzll(m0) : 0;
        int k1 = v1 ? __builtin_ctzll(m1) : 0;
        int k2 = v2 ? __builtin_ctzll(m2) : 0;
        int k3 = v3 ? __builtin_ctzll(m3) : 0;
        m0 &= m0 - 1; m1 &= m1 - 1; m2 &= m2 - 1; m3 &= m3 - 1;
        if (PO == 2) {
          // 4 independent LDS loads in flight
          float2 w0 = *(const float2*)&Wb[k0 * OH + lo2];
          float2 w1 = *(const float2*)&Wb[k1 * OH + lo2];
          float2 w2 = *(const float2*)&Wb[k2 * OH + lo2];
          float2 w3 = *(const float2*)&Wb[k3 * OH + lo2];
          // 4 independent acc chains; dead steps add exact +0.0f
          ax[0] += v0 ? w0.x : 0.f; ay[0] += v0 ? w0.y : 0.f;
          ax[1] += v1 ? w1.x : 0.f; ay[1] += v1 ? w1.y : 0.f;
          ax[2] += v2 ? w2.x : 0.f; ay[2] += v2 ? w2.y : 0.f;
          ax[3] += v3 ? w3.x : 0.f; ay[3] += v3 ? w3.y : 0.f;
        } else {
          float w0 = Wb[k0 * OH + lane];
          float w1 = Wb[k1 * OH + lane];
          float w2 = Wb[k2 * OH + lane];
          float w3 = Wb[k3 * OH + lane];
          ax[0] += v0 ? w0 : 0.f;
          ax[1] += v1 ? w1 : 0.f;
          ax[2] += v2 ? w2 : 0.f;
          ax[3] += v3 ? w3 : 0.f;
        }
      }
    }
    const int o0 = bo + lo2;
#pragma unroll
    for (int q = 0; q < 4; q++) {
      float* zp = Z + (size_t)(rbase + q * 16) * Zld + o0;
      if (PO == 2) {
        *(float2*)zp = make_float2(ax[q], ay[q]);
      } else {
        if (o0 < Ostore) zp[0] = ax[q];
      }
    }
  }
}

// ---------------------------------------------------------------------------
// CUBA LIF recurrence (depth-2 x U=25 pipeline). Exact per-step fp32
// mul/add chain. Mid layers emit SPIKE BITMASKS via __ballot
// (bit i = lane i = o = chunk*64+i).
// ---------------------------------------------------------------------------
template <bool FINAL>
__global__ __launch_bounds__(64) void cuba_kernel(
    const float* __restrict__ Z, unsigned long long* __restrict__ Mout,
    float* __restrict__ Fout, unsigned int* __restrict__ cnt, int O,
    int total) {
  int gid = blockIdx.x * 64 + threadIdx.x;
  const int mchunk = blockIdx.x & 3;  // o-chunk within 256 (non-final only)
  unsigned int c = 0;
  if (gid < total) {
    int b = gid / O;
    int o = gid - b * O;
    const int nb = b * TT;
    const float* zp = Z + (size_t)nb * O + o;
    float* fp = Fout + ((size_t)b * O + o) * TT;
    float cur = 0.f, volt = 0.f;
    constexpr int U = 25;
    float z0[U], z1[U];

#define LOADB(buf, tbase)                         \
  _Pragma("unroll") for (int u = 0; u < U; u++) { \
    buf[u] = zp[(size_t)((tbase) + u) * O];       \
  }
#define COMPB(buf, tbase)                                              \
  _Pragma("unroll") for (int u = 0; u < U; u++) {                      \
    cur = __fadd_rn(__fmul_rn(0.75f, cur), buf[u]);                    \
    volt = __fadd_rn(__fmul_rn(0.97f, volt), cur);                     \
    bool fire = volt >= 1.25f;                                         \
    volt = fire ? 0.f : volt;                                          \
    c += fire ? 1u : 0u;                                               \
    if (FINAL) {                                                       \
      fp[(tbase) + u] = fire ? 1.f : 0.f;                              \
    } else {                                                           \
      unsigned long long mm = __ballot(fire);                          \
      if (threadIdx.x == 0)                                            \
        Mout[(size_t)(nb + (tbase) + u) * 4 + mchunk] = mm;            \
    }                                                                  \
  }

    LOADB(z0, 0)
    for (int i = 0; i < 20; i++) {
      const int base = i * 2 * U;
      LOADB(z1, base + U)
      COMPB(z0, base)
      if (i < 19) LOADB(z0, base + 2 * U)
      COMPB(z1, base + U)
    }
#undef LOADB
#undef COMPB
  }
#pragma unroll
  for (int off = 32; off; off >>= 1) c += __shfl_down(c, off, 64);
  if ((threadIdx.x & 63) == 0) atomicAdd(cnt, c);
}

// ---------------------------------------------------------------------------
// Fused prep: cnt zero + input bitmask + 4 weight transposes.
// ---------------------------------------------------------------------------
__device__ __forceinline__ void prep_w_item(const float* __restrict__ W,
                                            float* __restrict__ Wt, int O,
                                            int K, int Opad, int i) {
  int k = i / Opad, o = i - k * Opad;
  Wt[i] = (k < K && o < O) ? W[(size_t)o * K + k] : 0.f;
}

__global__ __launch_bounds__(256) void prep_all(
    const float* __restrict__ X, const float* __restrict__ W1,
    const float* __restrict__ W2, const float* __restrict__ W3,
    const float* __restrict__ W4, unsigned long long* __restrict__ Min,
    float* __restrict__ Wt1, float* __restrict__ Wt2,
    float* __restrict__ Wt3, float* __restrict__ Wt4,
    unsigned int* __restrict__ cnt) {
  const int blk = blockIdx.x;
  const int tid = threadIdx.x;
  if (blk == 0 && tid < 8) cnt[tid] = 0u;
  if (blk < 250) {
    int gid = blk * 256 + tid;  // n
    unsigned long long msk = 0ull;
#pragma unroll
    for (int ch = 0; ch < 20; ch++) {
      float v = X[((size_t)(gid / TT) * 20 + ch) * TT + (gid % TT)];
      msk |= (unsigned long long)(v != 0.f ? 1u : 0u) << ch;
    }
    Min[gid] = msk;
  } else if (blk < 270) {  // W1t [20][256]: 5120 items
    prep_w_item(W1, Wt1, 256, 20, 256, (blk - 250) * 256 + tid);
  } else if (blk < 526) {  // W2t [256][256]
    prep_w_item(W2, Wt2, 256, 256, 256, (blk - 270) * 256 + tid);
  } else if (blk < 782) {  // W3t [256][256]
    prep_w_item(W3, Wt3, 256, 256, 256, (blk - 526) * 256 + tid);
  } else {                 // W4t [256][64]: 16384 items
    prep_w_item(W4, Wt4, 35, 256, 64, (blk - 782) * 256 + tid);
  }
}

__global__ void finalize_counts(const unsigned int* __restrict__ cnt,
                                float* __restrict__ out) {
  int i = threadIdx.x;
  if (i < 4) {
    const float denom[4] = {16384000.f, 16384000.f, 16384000.f, 2240000.f};
    out[i] = (float)cnt[i] / denom[i];
  }
}

// ---------------------------------------------------------------------------
extern "C" void kernel_launch(void* const* d_in, const int* in_sizes, int n_in,
                              void* d_out, int out_size, void* d_ws,
                              size_t ws_size, hipStream_t stream) {
  const float* X = (const float*)d_in[0];
  const float* W1 = (const float*)d_in[1];
  const float* W2 = (const float*)d_in[2];
  const float* W3 = (const float*)d_in[3];
  const float* W4 = (const float*)d_in[4];
  float* out = (float*)d_out;

  char* ws = (char*)d_ws;
  unsigned int* cnt = (unsigned int*)ws;               // 256 B
  float* Z = (float*)(ws + 256);                       // 65,536,000 B
  unsigned long long* Ma =
      (unsigned long long*)(ws + 256 + 65536000ull);   // 2,048,000 B
  unsigned long long* Mb = Ma + 256000ull;             // 2,048,000 B
  unsigned long long* Min = Mb + 256000ull;            // 512,000 B
  float* Wt1 = (float*)(Min + 64000ull);               // 20,480 B (16B-align)
  float* Wt2 = Wt1 + 5120;                             // 262,144 B
  float* Wt3 = Wt2 + 65536;                            // 262,144 B
  float* Wt4 = Wt3 + 65536;                            // 65,536 B

  prep_all<<<846, 256, 0, stream>>>(X, W1, W2, W3, W4, Min, Wt1, Wt2, Wt3,
                                    Wt4, cnt);

  // layer 1: K=20 (KC=1), O=256 in two 128-halves
  spmm<20, 1, 128, 2><<<dim3(125, 2), 1024, 0, stream>>>(
      Min, Wt1, Z, 256, 256, 256, 512);
  cuba_kernel<false><<<256, 64, 0, stream>>>(Z, Ma, nullptr, cnt + 0, 256,
                                             16384);
  // layer 2
  spmm<256, 4, 128, 2><<<dim3(125, 2), 1024, 0, stream>>>(
      Ma, Wt2, Z, 256, 256, 256, 512);
  cuba_kernel<false><<<256, 64, 0, stream>>>(Z, Mb, nullptr, cnt + 1, 256,
                                             16384);
  // layer 3
  spmm<256, 4, 128, 2><<<dim3(125, 2), 1024, 0, stream>>>(
      Mb, Wt3, Z, 256, 256, 256, 512);
  cuba_kernel<false><<<256, 64, 0, stream>>>(Z, Ma, nullptr, cnt + 2, 256,
                                             16384);
  // layer 4: O=35 (padded 64), PO=1, 64 KB LDS -> 2 blocks/CU
  spmm<256, 4, 64, 1><<<dim3(250, 1), 1024, 0, stream>>>(
      Ma, Wt4, Z, 64, 35, 35, 256);
  cuba_kernel<true><<<35, 64, 0, stream>>>(Z, nullptr, out, cnt + 3, 35, 2240);
  finalize_counts<<<1, 64, 0, stream>>>(cnt, out + 2240000);
}

// Round 8
// 533.506 us; speedup vs baseline: 1.7264x; 1.7264x over previous
//
#include <hip/hip_runtime.h>
#include <cstdint>
#include <cstddef>

#define TT 1000
#define NB 64000  // B*T

// ---------------------------------------------------------------------------
// NUMERICS CONTRACT (verified absmax 0.0 across sessions): each z[n,o] is
// ONE ascending-k fp32 fmaf chain. Do not reorder, split, or tree-reduce.
// pk (f32x2) packing across o-pairs is exact (each element an IEEE fmaf).
//
// LEDGER:
//  dense r0/r1: 106-108us/gemm, busy-work 72us invariant, ~30% idle
//    immovable (occupancy r1, tile r2, counted-vmcnt r3/r4 all failed).
//  sparse r5/r6/r7: 148-300us/spmm — latency/select-bound, DEAD (chain
//    contract forbids cross-lane k parallelism).
//  r8: time-budget arithmetic shows the 4 cuba dispatches ~47us each
//    (~190us total, 40% of pipeline) — r1's mid cuba does scattered u8
//    byte-stores (8x write amplification) at 1 wave/CU. Fix: ballot mask
//    emission (proven r5) + coalesced expand kernel -> same u8 A-image for
//    the proven dense gemms. Mask buffer aliases dead Sin region.
// ---------------------------------------------------------------------------

typedef __attribute__((ext_vector_type(2))) float f32x2;

// async global->LDS DMA: 16B/lane; LDS dest = wave-uniform base + lane*16;
// global src per-lane.
__device__ __forceinline__ void dma16(const void* g, void* l) {
  __builtin_amdgcn_global_load_lds(
      (const __attribute__((address_space(1))) unsigned int*)g,
      (__attribute__((address_space(3))) unsigned int*)l, 16, 0, 0);
}

// ---------------------------------------------------------------------------
// A image (DMA-ready): u32 idx = (n>>7)*(K/16)*512 + kt16*512 + kd*128
//   + (n&127); byte = k&3, kd = (k>>2)&3.  16-k chunks are contiguous, so a
//   BK=32 tile = 1024 contiguous dwords (two 512 halves).
// W: plain transposed [K][Opad] f32.
// ---------------------------------------------------------------------------

// ---------------------------------------------------------------------------
// gemm_dma BK=32 (r1, proven 106us): 128n x 128o block, 256 thr, 8x8/thread
// (pk f32x2). Double-buffered LDS (40 KB), ONE barrier per 32-k tile.
// Zero-VGPR global_load_lds staging for both A (u8-packed) and B.
// ---------------------------------------------------------------------------
__global__ __launch_bounds__(256) void gemm_dma(
    const unsigned int* __restrict__ Aswz, const float* __restrict__ Wt,
    float* __restrict__ Z, int KT32, int Wld, int Zld, int Ostore) {
  __shared__ unsigned int AsU[2][1024];        // 32k x 128row packed u8
  __shared__ __align__(16) float Bs[2][4096];  // 32k x 128o
  const int t = threadIdx.x;
  const int lane = t & 63;
  const int wave = t >> 6;
  const int bn = blockIdx.x * 128;
  const int bo = blockIdx.y * 128;
  const int tx4 = (t & 15) * 4;
  const int ty4 = ((t >> 4) & 15) * 4;

  // B DMA geometry: wave covers rows 2w..2w+1 (+8d per dma d)
  const int f0 = wave * 64 + lane;
  const int bk0 = f0 >> 5;
  const int bc0 = (f0 & 31) * 4;
  const float* wsrc = Wt + (size_t)bk0 * Wld + bo + bc0;
  // A DMA: 4 waves x 256 dwords = 1024 dwords (one 32-k tile)
  const unsigned int* asrc =
      Aswz + (size_t)blockIdx.x * KT32 * 1024 + wave * 256 + lane * 4;

  f32x2 acc[8][4];
#pragma unroll
  for (int j = 0; j < 8; j++)
#pragma unroll
    for (int i = 0; i < 4; i++) {
      acc[j][i][0] = 0.f;
      acc[j][i][1] = 0.f;
    }

  // prologue: stage tile 0
#pragma unroll
  for (int d = 0; d < 4; d++)
    dma16(wsrc + (size_t)(8 * d) * Wld, &Bs[0][1024 * d + wave * 256]);
  dma16(asrc, &AsU[0][wave * 256]);
  __syncthreads();

  for (int tile = 0; tile < KT32; tile++) {
    const int cur = tile & 1, nxt = cur ^ 1;
    if (tile + 1 < KT32) {  // zero-VGPR async prefetch, lands during compute
      const float* wn = wsrc + (size_t)(tile + 1) * 32 * Wld;
#pragma unroll
      for (int d = 0; d < 4; d++)
        dma16(wn + (size_t)(8 * d) * Wld, &Bs[nxt][1024 * d + wave * 256]);
      dma16(asrc + (size_t)(tile + 1) * 1024, &AsU[nxt][wave * 256]);
    }
#pragma unroll
    for (int kh = 0; kh < 2; kh++) {
#pragma unroll
      for (int kq = 0; kq < 4; kq++) {
        uint4 a0 = *(const uint4*)&AsU[cur][kh * 512 + kq * 128 + ty4];
        uint4 a1 = *(const uint4*)&AsU[cur][kh * 512 + kq * 128 + 64 + ty4];
#pragma unroll
        for (int k2 = 0; k2 < 4; k2++) {
          const int kk = kh * 16 + kq * 4 + k2;
          const int sh = k2 * 8;
          float av[8];
          av[0] = (float)((a0.x >> sh) & 0xffu);  // v_cvt_f32_ubyte
          av[1] = (float)((a0.y >> sh) & 0xffu);
          av[2] = (float)((a0.z >> sh) & 0xffu);
          av[3] = (float)((a0.w >> sh) & 0xffu);
          av[4] = (float)((a1.x >> sh) & 0xffu);
          av[5] = (float)((a1.y >> sh) & 0xffu);
          av[6] = (float)((a1.z >> sh) & 0xffu);
          av[7] = (float)((a1.w >> sh) & 0xffu);
          float4 b0 = *(const float4*)&Bs[cur][kk * 128 + tx4];
          float4 b1 = *(const float4*)&Bs[cur][kk * 128 + 64 + tx4];
          f32x2 bp[4];
          bp[0][0] = b0.x; bp[0][1] = b0.y;
          bp[1][0] = b0.z; bp[1][1] = b0.w;
          bp[2][0] = b1.x; bp[2][1] = b1.y;
          bp[3][0] = b1.z; bp[3][1] = b1.w;
#pragma unroll
          for (int j = 0; j < 8; j++) {
            f32x2 a2;
            a2[0] = av[j];
            a2[1] = av[j];
#pragma unroll
            for (int i = 0; i < 4; i++)
              acc[j][i] = __builtin_elementwise_fma(a2, bp[i], acc[j][i]);
          }
        }
      }
    }
    __syncthreads();
  }

#pragma unroll
  for (int jp = 0; jp < 2; jp++) {
#pragma unroll
    for (int j = 0; j < 4; j++) {
      int n = bn + jp * 64 + ty4 + j;
#pragma unroll
      for (int ip = 0; ip < 2; ip++) {
        int o0 = bo + ip * 64 + tx4;
        f32x2 p0 = acc[jp * 4 + j][ip * 2];
        f32x2 p1 = acc[jp * 4 + j][ip * 2 + 1];
        float* zp = Z + (size_t)n * Zld + o0;
        if (o0 + 3 < Ostore) {
          *(float4*)zp = make_float4(p0[0], p0[1], p1[0], p1[1]);
        } else {
          float aq[4] = {p0[0], p0[1], p1[0], p1[1]};
#pragma unroll
          for (int q = 0; q < 4; q++)
            if (o0 + q < Ostore) zp[q] = aq[q];
        }
      }
    }
  }
}

// ---------------------------------------------------------------------------
// gemm_l4 (proven): layer 4, O=35 padded 64. 256n x 64o block, BK=16.
// Packed f32x2 FMA (contract-safe, r1-verified).
// ---------------------------------------------------------------------------
__global__ __launch_bounds__(256) void gemm_l4(
    const unsigned int* __restrict__ Aswz, const float* __restrict__ Wt,
    float* __restrict__ Z) {
  const int KT = 16, OS = 35;
  __shared__ unsigned int Al[2][1024];
  __shared__ __align__(16) float Bl[2][1024];
  const int t = threadIdx.x;
  const int lane = t & 63;
  const int wave = t >> 6;
  const int bn = blockIdx.x * 256;
  const int h = wave >> 1;
  const int ny = (lane >> 3) * 8;
  const int ox = (lane & 7) * 8;
  const int lrow = (wave & 1) * 64 + ny;

  const unsigned int* asrc = Aswz +
      (size_t)(blockIdx.x * 2 + (wave >> 1)) * KT * 512 + (wave & 1) * 256 +
      lane * 4;
  const float* wsrc = Wt + wave * 256 + lane * 4;

  f32x2 acc[8][4];
#pragma unroll
  for (int j = 0; j < 8; j++)
#pragma unroll
    for (int i = 0; i < 4; i++) {
      acc[j][i][0] = 0.f;
      acc[j][i][1] = 0.f;
    }

  dma16(asrc, &Al[0][wave * 256]);
  dma16(wsrc, &Bl[0][wave * 256]);
  __syncthreads();

  for (int tile = 0; tile < KT; tile++) {
    const int cur = tile & 1, nxt = cur ^ 1;
    if (tile + 1 < KT) {
      dma16(asrc + (size_t)(tile + 1) * 512, &Al[nxt][wave * 256]);
      dma16(wsrc + (size_t)(tile + 1) * 1024, &Bl[nxt][wave * 256]);
    }
#pragma unroll
    for (int kq = 0; kq < 4; kq++) {
      uint4 a0 = *(const uint4*)&Al[cur][h * 512 + kq * 128 + lrow];
      uint4 a1 = *(const uint4*)&Al[cur][h * 512 + kq * 128 + lrow + 4];
#pragma unroll
      for (int k2 = 0; k2 < 4; k2++) {
        const int kk = kq * 4 + k2;
        const int sh = k2 * 8;
        float av[8];
        av[0] = (float)((a0.x >> sh) & 0xffu);
        av[1] = (float)((a0.y >> sh) & 0xffu);
        av[2] = (float)((a0.z >> sh) & 0xffu);
        av[3] = (float)((a0.w >> sh) & 0xffu);
        av[4] = (float)((a1.x >> sh) & 0xffu);
        av[5] = (float)((a1.y >> sh) & 0xffu);
        av[6] = (float)((a1.z >> sh) & 0xffu);
        av[7] = (float)((a1.w >> sh) & 0xffu);
        float4 b0 = *(const float4*)&Bl[cur][kk * 64 + ox];
        float4 b1 = *(const float4*)&Bl[cur][kk * 64 + ox + 4];
        f32x2 bp[4];
        bp[0][0] = b0.x; bp[0][1] = b0.y;
        bp[1][0] = b0.z; bp[1][1] = b0.w;
        bp[2][0] = b1.x; bp[2][1] = b1.y;
        bp[3][0] = b1.z; bp[3][1] = b1.w;
#pragma unroll
        for (int j = 0; j < 8; j++) {
          f32x2 a2;
          a2[0] = av[j];
          a2[1] = av[j];
#pragma unroll
          for (int i = 0; i < 4; i++)
            acc[j][i] = __builtin_elementwise_fma(a2, bp[i], acc[j][i]);
        }
      }
    }
    __syncthreads();
  }

#pragma unroll
  for (int j = 0; j < 8; j++) {
    int n = bn + wave * 64 + ny + j;
    float* zp = Z + (size_t)n * OS + ox;
    if (ox + 7 < OS) {
      *(float4*)zp =
          make_float4(acc[j][0][0], acc[j][0][1], acc[j][1][0], acc[j][1][1]);
      *(float4*)(zp + 4) =
          make_float4(acc[j][2][0], acc[j][2][1], acc[j][3][0], acc[j][3][1]);
    } else {
      float aq[8] = {acc[j][0][0], acc[j][0][1], acc[j][1][0], acc[j][1][1],
                     acc[j][2][0], acc[j][2][1], acc[j][3][0], acc[j][3][1]};
#pragma unroll
      for (int q = 0; q < 8; q++)
        if (ox + q < OS) zp[q] = aq[q];
    }
  }
}

// ---------------------------------------------------------------------------
// CUBA LIF recurrence (depth-2 x U=25 pipeline, proven). Exact per-step
// fp32 mul/add chain. Mid layers emit SPIKE BITMASKS via __ballot (bit i =
// lane i = o&63; word = o>>6) — one coalesced u64 store per wave per t
// instead of r1's 64 scattered u8 stores (8x write amplification at
// 1 wave/CU was ~half the cuba cost).
// ---------------------------------------------------------------------------
template <bool FINAL>
__global__ __launch_bounds__(64) void cuba_kernel(
    const float* __restrict__ Z, unsigned long long* __restrict__ Mout,
    float* __restrict__ Fout, unsigned int* __restrict__ cnt, int O,
    int total) {
  int gid = blockIdx.x * 64 + threadIdx.x;
  const int mchunk = blockIdx.x & 3;  // o-chunk within 256 (non-final only)
  unsigned int c = 0;
  if (gid < total) {
    int b = gid / O;
    int o = gid - b * O;
    const int nb = b * TT;
    const float* zp = Z + (size_t)nb * O + o;
    float* fp = Fout + ((size_t)b * O + o) * TT;
    float cur = 0.f, volt = 0.f;
    constexpr int U = 25;
    float z0[U], z1[U];

#define LOADB(buf, tbase)                         \
  _Pragma("unroll") for (int u = 0; u < U; u++) { \
    buf[u] = zp[(size_t)((tbase) + u) * O];       \
  }
#define COMPB(buf, tbase)                                              \
  _Pragma("unroll") for (int u = 0; u < U; u++) {                      \
    cur = __fadd_rn(__fmul_rn(0.75f, cur), buf[u]);                    \
    volt = __fadd_rn(__fmul_rn(0.97f, volt), cur);                     \
    bool fire = volt >= 1.25f;                                         \
    volt = fire ? 0.f : volt;                                          \
    c += fire ? 1u : 0u;                                               \
    if (FINAL) {                                                       \
      fp[(tbase) + u] = fire ? 1.f : 0.f;                              \
    } else {                                                           \
      unsigned long long mm = __ballot(fire);                          \
      if (threadIdx.x == 0)                                            \
        Mout[(size_t)(nb + (tbase) + u) * 4 + mchunk] = mm;            \
    }                                                                  \
  }

    LOADB(z0, 0)
    for (int i = 0; i < 20; i++) {
      const int base = i * 2 * U;
      LOADB(z1, base + U)
      COMPB(z0, base)
      if (i < 19) LOADB(z0, base + 2 * U)
      COMPB(z1, base + U)
    }
#undef LOADB
#undef COMPB
  }
#pragma unroll
  for (int off = 32; off; off >>= 1) c += __shfl_down(c, off, 64);
  if ((threadIdx.x & 63) == 0) atomicAdd(cnt, c);
}

// ---------------------------------------------------------------------------
// expand_mask: masks (u64, word = n*4 + (k>>6), bit = k&63) -> u8 A-image
// dword gid = (n>>7)*8192 + kt16*512 + kd*128 + (n&127); byte j = k&3 holds
// 0/1 for k = kt16*16 + kd*4 + j. Fully coalesced 16 MB write, 2 MB read.
// ---------------------------------------------------------------------------
__global__ __launch_bounds__(256) void expand_mask(
    const unsigned long long* __restrict__ Mm,
    unsigned int* __restrict__ Img) {
  int gid = blockIdx.x * 256 + threadIdx.x;  // dword index, 4,096,000 total
  int n7 = gid >> 13;
  int rem = gid & 8191;
  int kt16 = rem >> 9;
  int rem2 = rem & 511;
  int kd = rem2 >> 7;
  int nl = rem2 & 127;
  int n = n7 * 128 + nl;
  unsigned long long m = Mm[n * 4 + (kt16 >> 2)];
  int b = (kt16 & 3) * 16 + kd * 4;
  unsigned v = (unsigned)((m >> b) & 0xFull);
  Img[gid] = (v & 1u) | ((v & 2u) << 7) | ((v & 4u) << 14) | ((v & 8u) << 21);
}

// ---------------------------------------------------------------------------
// Fused prep (r1, proven): cnt zero + input u8 image (K=32 padded) + 4
// weight transposes (Wt1 K-padded to 32).
// ---------------------------------------------------------------------------
__device__ __forceinline__ void prep_w_item(const float* __restrict__ W,
                                            float* __restrict__ Wt, int O,
                                            int K, int Opad, int i) {
  int k = i / Opad, o = i - k * Opad;
  Wt[i] = (k < K && o < O) ? W[(size_t)o * K + k] : 0.f;
}

__global__ __launch_bounds__(256) void prep_all(
    const float* __restrict__ X, const float* __restrict__ W1,
    const float* __restrict__ W2, const float* __restrict__ W3,
    const float* __restrict__ W4, unsigned int* __restrict__ Ain,
    float* __restrict__ Wt1, float* __restrict__ Wt2,
    float* __restrict__ Wt3, float* __restrict__ Wt4,
    unsigned int* __restrict__ cnt) {
  const int blk = blockIdx.x;
  const int tid = threadIdx.x;
  if (blk == 0 && tid < 8) cnt[tid] = 0u;
  if (blk < 250) {
    int gid = blk * 256 + tid;  // n
    unsigned int w[8];
#pragma unroll
    for (int i = 0; i < 8; i++) w[i] = 0u;
#pragma unroll
    for (int c = 0; c < 20; c++) {
      float v = X[((size_t)(gid / TT) * 20 + c) * TT + (gid % TT)];
      w[c >> 2] |= (v != 0.f ? 1u : 0u) << ((c & 3) * 8);
    }
    // A image (K=32): idx = (n>>7)*1024 + k16*512 + kd*128 + (n&127)
    unsigned int base = (gid >> 7) * 1024 + (gid & 127);
#pragma unroll
    for (int kd8 = 0; kd8 < 8; kd8++)
      Ain[base + (kd8 >> 2) * 512 + (kd8 & 3) * 128] = w[kd8];
  } else if (blk < 282) {
    prep_w_item(W1, Wt1, 256, 20, 256, (blk - 250) * 256 + tid);
  } else if (blk < 538) {
    prep_w_item(W2, Wt2, 256, 256, 256, (blk - 282) * 256 + tid);
  } else if (blk < 794) {
    prep_w_item(W3, Wt3, 256, 256, 256, (blk - 538) * 256 + tid);
  } else {
    prep_w_item(W4, Wt4, 35, 256, 64, (blk - 794) * 256 + tid);
  }
}

__global__ void finalize_counts(const unsigned int* __restrict__ cnt,
                                float* __restrict__ out) {
  int i = threadIdx.x;
  if (i < 4) {
    const float denom[4] = {16384000.f, 16384000.f, 16384000.f, 2240000.f};
    out[i] = (float)cnt[i] / denom[i];
  }
}

// ---------------------------------------------------------------------------
extern "C" void kernel_launch(void* const* d_in, const int* in_sizes, int n_in,
                              void* d_out, int out_size, void* d_ws,
                              size_t ws_size, hipStream_t stream) {
  const float* X = (const float*)d_in[0];
  const float* W1 = (const float*)d_in[1];
  const float* W2 = (const float*)d_in[2];
  const float* W3 = (const float*)d_in[3];
  const float* W4 = (const float*)d_in[4];
  float* out = (float*)d_out;

  char* ws = (char*)d_ws;
  unsigned int* cnt = (unsigned int*)ws;                       // 256 B
  float* Z = (float*)(ws + 256);                               // 65,536,000
  unsigned int* Sa = (unsigned int*)(ws + 256 + 65536000ull);  // 16,384,000
  unsigned int* Sb = Sa + 4096000ull;                          // 16,384,000
  unsigned int* Sin = Sb + 4096000ull;                         // 2,048,000
  float* Wt1 = (float*)(Sin + 512000ull);                      // 8192 f
  float* Wt2 = Wt1 + 8192;                                     // 65536 f
  float* Wt3 = Wt2 + 65536;                                    // 65536 f
  float* Wt4 = Wt3 + 65536;                                    // 16384 f
  // mask buffer aliases Sin (dead after gemm1; 2,048,000 B = 64000*4 u64)
  unsigned long long* Mm = (unsigned long long*)Sin;

  prep_all<<<858, 256, 0, stream>>>(X, W1, W2, W3, W4, Sin, Wt1, Wt2, Wt3,
                                    Wt4, cnt);

  dim3 gBig(500, 2);

  gemm_dma<<<gBig, 256, 0, stream>>>(Sin, Wt1, Z, 1, 256, 256, 256);
  cuba_kernel<false><<<256, 64, 0, stream>>>(Z, Mm, nullptr, cnt + 0, 256,
                                             16384);
  expand_mask<<<16000, 256, 0, stream>>>(Mm, Sa);
  gemm_dma<<<gBig, 256, 0, stream>>>(Sa, Wt2, Z, 8, 256, 256, 256);
  cuba_kernel<false><<<256, 64, 0, stream>>>(Z, Mm, nullptr, cnt + 1, 256,
                                             16384);
  expand_mask<<<16000, 256, 0, stream>>>(Mm, Sb);
  gemm_dma<<<gBig, 256, 0, stream>>>(Sb, Wt3, Z, 8, 256, 256, 256);
  cuba_kernel<false><<<256, 64, 0, stream>>>(Z, Mm, nullptr, cnt + 2, 256,
                                             16384);
  expand_mask<<<16000, 256, 0, stream>>>(Mm, Sa);
  gemm_l4<<<250, 256, 0, stream>>>(Sa, Wt4, Z);
  cuba_kernel<true><<<35, 64, 0, stream>>>(Z, nullptr, out, cnt + 3, 35, 2240);
  finalize_counts<<<1, 64, 0, stream>>>(cnt, out + 2240000);
}